// Round 3
// baseline (673.322 us; speedup 1.0000x reference)
//
#include <hip/hip_runtime.h>
#include <stdint.h>

#define B_ROWS 8192
#define K_DIM 2048
#define N_DIM 2048
#define NPOP 8

typedef float f32x4 __attribute__((ext_vector_type(4)));
typedef __bf16 bf16x8 __attribute__((ext_vector_type(8)));

__device__ __forceinline__ unsigned short f2bf(float f) {
  unsigned int u = __float_as_uint(f);
  u += 0x7fffu + ((u >> 16) & 1u);   // round-to-nearest-even
  return (unsigned short)(u >> 16);
}

// async global->LDS, 16B/lane; LDS dest = wave-uniform base + lane*16
__device__ __forceinline__ void glds16(const unsigned short* g, unsigned short* l) {
  __builtin_amdgcn_global_load_lds(
      (__attribute__((address_space(1))) unsigned int*)g,
      (__attribute__((address_space(3))) unsigned int*)l, 16, 0, 0);
}

// ---- W fp32 -> bf16 ----
__global__ void prep_w_kernel(const float* __restrict__ W, unsigned short* __restrict__ Wb) {
  const int n4 = NPOP * N_DIM * K_DIM / 4;
  int stride = gridDim.x * blockDim.x;
  for (int i = blockIdx.x * blockDim.x + threadIdx.x; i < n4; i += stride) {
    float4 v = reinterpret_cast<const float4*>(W)[i];
    ushort4 s;
    s.x = f2bf(v.x); s.y = f2bf(v.y); s.z = f2bf(v.z); s.w = f2bf(v.w);
    reinterpret_cast<ushort4*>(Wb)[i] = s;
  }
}

// ---- selector (fp32, Ws staged in LDS) + x->bf16 conversion, 16 rows/block ----
__global__ __launch_bounds__(256) void sel_conv_x_kernel(
    const float* __restrict__ x, const float* __restrict__ Ws,
    const float* __restrict__ bs, unsigned short* __restrict__ xb,
    int* __restrict__ sel) {
  __shared__ float ws_l[NPOP * K_DIM];   // 64 KB -> 2 blocks/CU
  const int t = threadIdx.x;
  const float4* Ws4 = reinterpret_cast<const float4*>(Ws);
  float4* wsl4 = reinterpret_cast<float4*>(ws_l);
#pragma unroll
  for (int i = 0; i < NPOP * K_DIM / 4 / 256; ++i)
    wsl4[i * 256 + t] = Ws4[i * 256 + t];
  __syncthreads();

  const int w = t >> 6, l = t & 63;
  const float4* x4 = reinterpret_cast<const float4*>(x);

  for (int rr = 0; rr < 4; ++rr) {          // 4 rows per wave, 16 per block
    int r = blockIdx.x * 16 + rr * 4 + w;
    float acc[NPOP];
#pragma unroll
    for (int p = 0; p < NPOP; ++p) acc[p] = 0.f;
#pragma unroll
    for (int j = 0; j < 8; ++j) {
      int idx = j * 256 + l * 4;
      float4 v = x4[(r * K_DIM + idx) >> 2];
      ushort4 s; s.x = f2bf(v.x); s.y = f2bf(v.y); s.z = f2bf(v.z); s.w = f2bf(v.w);
      *reinterpret_cast<ushort4*>(xb + (size_t)r * K_DIM + idx) = s;
#pragma unroll
      for (int p = 0; p < NPOP; ++p) {
        float4 wv = wsl4[(p * K_DIM + idx) >> 2];
        acc[p] += v.x * wv.x + v.y * wv.y + v.z * wv.z + v.w * wv.w;
      }
    }
#pragma unroll
    for (int off = 32; off > 0; off >>= 1)
#pragma unroll
      for (int p = 0; p < NPOP; ++p) acc[p] += __shfl_xor(acc[p], off, 64);
    if (l == 0) {
      float lg[NPOP];
#pragma unroll
      for (int p = 0; p < NPOP; ++p) lg[p] = acc[p] + bs[p];
      int p1 = 0;
#pragma unroll
      for (int p = 1; p < NPOP; ++p) if (lg[p] > lg[p1]) p1 = p;  // strict >: low idx wins ties
      int p2 = -1;
#pragma unroll
      for (int p = 0; p < NPOP; ++p) {
        if (p == p1) continue;
        if (p2 < 0 || lg[p] > lg[p2]) p2 = p;
      }
      sel[r] = p1 * 8 + p2;
    }
  }
}

// ---- build per-(slot,expert) row lists deterministically ----
__global__ __launch_bounds__(256) void build_lists_kernel(const int* __restrict__ sel,
                                                          int* __restrict__ lists,
                                                          int* __restrict__ cnt) {
  const int lid  = blockIdx.x;      // 0..15
  const int slot = lid >> 3;
  const int ex   = lid & 7;
  const int t    = threadIdx.x;
  __shared__ int psum[256];
  int local[32];
  int c = 0;
#pragma unroll
  for (int i = 0; i < 32; ++i) {
    int r = i * 256 + t;
    int s = sel[r];
    int e = slot ? (s & 7) : (s >> 3);
    if (e == ex) local[c++] = r;
  }
  psum[t] = c;
  __syncthreads();
  for (int off = 1; off < 256; off <<= 1) {
    int v = (t >= off) ? psum[t - off] : 0;
    __syncthreads();
    psum[t] += v;
    __syncthreads();
  }
  int start = psum[t] - c;
  for (int i = 0; i < c; ++i) lists[lid * 2048 + start + i] = local[i];
  if (t == 255) cnt[lid] = psum[255];
}

// ---- grouped GEMM, 256x128 tile, 8 waves, BK=32, XOR-swizzled LDS ----
// swizzle: chunk position c of row r holds global k-chunk c ^ ((r>>1)&3)
__global__ __launch_bounds__(512, 4) void gemm_kernel(
    const unsigned short* __restrict__ xb,
    const unsigned short* __restrict__ Wb,
    const float* __restrict__ bvec,
    const int* __restrict__ lists,
    const int* __restrict__ cnt,
    float* __restrict__ out,
    int pass) {
  const int g   = blockIdx.z;
  const int lid = pass * 8 + g;
  const int cg  = cnt[lid];
  const int m0  = blockIdx.x * 256;
  if (m0 >= cg) return;
  const int n0 = blockIdx.y * 128;

  __shared__ __align__(16) unsigned short As[256 * 32];   // 16 KB
  __shared__ __align__(16) unsigned short Bs[128 * 32];   // 8 KB
  __shared__ int   sh_rows[256];
  __shared__ float sh_bias[128];

  const int t = threadIdx.x;
  const int w = t >> 6;     // 0..7
  const int l = t & 63;

  const int* list = lists + lid * 2048;
  if (t < 256) { int idx = m0 + t; sh_rows[t] = (idx < cg) ? list[idx] : -1; }
  else if (t < 384) sh_bias[t - 256] = bvec[g * N_DIM + n0 + (t - 256)];
  __syncthreads();

  // staging: wave w loads A tile-rows [32w,32w+15] & [32w+16,32w+31], B rows [16w,16w+15]
  const int rg = l >> 2;       // row within 16-group
  const int ck = l & 3;        // chunk position
  const int tra0 = 32 * w + rg;
  const int tra1 = tra0 + 16;
  int ar0 = sh_rows[tra0]; if (ar0 < 0) ar0 = 0;
  int ar1 = sh_rows[tra1]; if (ar1 < 0) ar1 = 0;
  const unsigned short* ap0 = xb + (size_t)ar0 * K_DIM + ((ck ^ ((tra0 >> 1) & 3)) * 8);
  const unsigned short* ap1 = xb + (size_t)ar1 * K_DIM + ((ck ^ ((tra1 >> 1) & 3)) * 8);
  const int trb = 16 * w + rg;
  const unsigned short* wbase = Wb + (size_t)g * N_DIM * K_DIM;
  const unsigned short* bp = wbase + (size_t)(n0 + trb) * K_DIM + ((ck ^ ((trb >> 1) & 3)) * 8);

  unsigned short* As_d0 = As + (2 * w) * 512;
  unsigned short* As_d1 = As + (2 * w + 1) * 512;
  unsigned short* Bs_d  = Bs + w * 512;

  const int wm = w >> 1, wn = w & 1;
  const int lane16 = l & 15;
  const int quad   = l >> 4;

  // k-invariant swizzled fragment addresses
  const unsigned short* afp[4];
  const unsigned short* bfp[4];
#pragma unroll
  for (int mi = 0; mi < 4; ++mi) {
    int r = wm * 64 + mi * 16 + lane16;
    afp[mi] = &As[r * 32 + ((quad ^ ((r >> 1) & 3)) * 8)];
  }
#pragma unroll
  for (int ni = 0; ni < 4; ++ni) {
    int r = wn * 64 + ni * 16 + lane16;
    bfp[ni] = &Bs[r * 32 + ((quad ^ ((r >> 1) & 3)) * 8)];
  }

  f32x4 acc[4][4];
#pragma unroll
  for (int i = 0; i < 4; ++i)
#pragma unroll
    for (int j = 0; j < 4; ++j) { f32x4 z = {0.f, 0.f, 0.f, 0.f}; acc[i][j] = z; }

  for (int k0 = 0; k0 < K_DIM; k0 += 32) {
    glds16(ap0 + k0, As_d0);
    glds16(ap1 + k0, As_d1);
    glds16(bp  + k0, Bs_d);
    __syncthreads();

    bf16x8 af[4], bf[4];
#pragma unroll
    for (int mi = 0; mi < 4; ++mi) af[mi] = *reinterpret_cast<const bf16x8*>(afp[mi]);
#pragma unroll
    for (int ni = 0; ni < 4; ++ni) bf[ni] = *reinterpret_cast<const bf16x8*>(bfp[ni]);
#pragma unroll
    for (int mi = 0; mi < 4; ++mi)
#pragma unroll
      for (int ni = 0; ni < 4; ++ni)
        acc[mi][ni] = __builtin_amdgcn_mfma_f32_16x16x32_bf16(af[mi], bf[ni], acc[mi][ni], 0, 0, 0);
    __syncthreads();
  }

  // epilogue: C/D layout col=lane&15, row=quad*4+reg
#pragma unroll
  for (int mi = 0; mi < 4; ++mi) {
#pragma unroll
    for (int i = 0; i < 4; ++i) {
      int trow = wm * 64 + mi * 16 + quad * 4 + i;
      int r = sh_rows[trow];
      if (r < 0) continue;
      float* orow = out + (size_t)r * N_DIM + n0;
#pragma unroll
      for (int ni = 0; ni < 4; ++ni) {
        int colL = wn * 64 + ni * 16 + lane16;
        float v = 0.5f * acc[mi][ni][i] + 0.5f * sh_bias[colL];
        if (pass == 0) orow[colL] = v;
        else           orow[colL] += v;
      }
    }
  }
}

extern "C" void kernel_launch(void* const* d_in, const int* in_sizes, int n_in,
                              void* d_out, int out_size, void* d_ws, size_t ws_size,
                              hipStream_t stream) {
  const float* x  = (const float*)d_in[0];
  const float* W  = (const float*)d_in[1];
  const float* b  = (const float*)d_in[2];
  const float* Ws = (const float*)d_in[3];
  const float* bs = (const float*)d_in[4];
  float* out = (float*)d_out;

  // ws: Wb bf16 (64MiB) | xb bf16 (32MiB) | lists 16*2048 int | cnt 16 int | sel 8192 int
  char* ws = (char*)d_ws;
  unsigned short* Wb = (unsigned short*)ws;
  unsigned short* xb = (unsigned short*)(ws + (size_t)67108864);
  int* lists = (int*)(ws + (size_t)67108864 + 33554432);
  int* cnt   = (int*)(ws + (size_t)67108864 + 33554432 + 131072);
  int* sel   = (int*)(ws + (size_t)67108864 + 33554432 + 131072 + 4096);

  prep_w_kernel<<<4096, 256, 0, stream>>>(W, Wb);
  sel_conv_x_kernel<<<512, 256, 0, stream>>>(x, Ws, bs, xb, sel);
  build_lists_kernel<<<16, 256, 0, stream>>>(sel, lists, cnt);
  gemm_kernel<<<dim3(8, 16, 8), 512, 0, stream>>>(xb, Wb, b, lists, cnt, out, 0);
  gemm_kernel<<<dim3(8, 16, 8), 512, 0, stream>>>(xb, Wb, b, lists, cnt, out, 1);
}